// Round 6
// baseline (129.446 us; speedup 1.0000x reference)
//
#include <hip/hip_runtime.h>
#include <hip/hip_bf16.h>

// Shapes (fixed for this problem)
#define BB 2
#define NN 16
#define CC 256
#define KK 64
#define HW 4096
#define NH 8

typedef __attribute__((ext_vector_type(4))) float f32x4;
typedef __attribute__((ext_vector_type(8))) short s16x8;
typedef __attribute__((ext_vector_type(4))) short s16x4;

__device__ __forceinline__ short f2bf(float f) {
    __hip_bfloat16 h = __float2bfloat16(f);
    return *reinterpret_cast<short*>(&h);
}
__device__ __forceinline__ float bf2f(short s) {
    unsigned int u = ((unsigned int)(unsigned short)s) << 16;
    float f; __builtin_memcpy(&f, &u, 4); return f;
}

// ---------------------------------------------------------------------------
// K1: key_n = softmax(key_map, axis=K). Two lanes per hw (32 k each), shfl_xor
// combine. Emits kbf bf16 [b][k][hw] and kbfT bf16 [b][hw][k].
// grid = BB * HW/32 = 256 blocks of 1 wave.
// ---------------------------------------------------------------------------
__global__ __launch_bounds__(64) void k_softmax(const float* __restrict__ km,
                                                short* __restrict__ kbf,
                                                short* __restrict__ kbfT) {
    const int b = blockIdx.x >> 7;                  // 128 blocks per b
    const int hw = (blockIdx.x & 127) * 32 + (threadIdx.x & 31);
    const int half = threadIdx.x >> 5;              // k in [half*32, half*32+32)
    const float* p = km + ((size_t)b * KK + half * 32) * HW + hw;
    float x[32];
    float m = -1e30f;
#pragma unroll
    for (int k = 0; k < 32; k++) { x[k] = p[(size_t)k * HW]; m = fmaxf(m, x[k]); }
    m = fmaxf(m, __shfl_xor(m, 32, 64));
    float s = 0.f;
#pragma unroll
    for (int k = 0; k < 32; k++) { x[k] = __expf(x[k] - m); s += x[k]; }
    s += __shfl_xor(s, 32, 64);
    const float inv = 1.f / s;
    short* q2 = kbf + ((size_t)b * KK + half * 32) * HW + hw;
#pragma unroll
    for (int k = 0; k < 32; k++) {
        x[k] *= inv;
        q2[(size_t)k * HW] = f2bf(x[k]);
    }
    short* q3 = kbfT + ((size_t)b * HW + hw) * KK + half * 32;
#pragma unroll
    for (int k8 = 0; k8 < 32; k8 += 8) {
        s16x8 v;
#pragma unroll
        for (int j = 0; j < 8; j++) v[j] = f2bf(x[k8 + j]);
        *(s16x8*)(q3 + k8) = v;
    }
}

// ---------------------------------------------------------------------------
// K2: gram[b,k,j] = sum_hw kn[b,k,hw]*kn[b,j,hw]. Symmetric: block per (b, k>=j),
// mirror store. bf16 input, f32 accumulate.
// ---------------------------------------------------------------------------
__global__ __launch_bounds__(256) void k_gram(const short* __restrict__ kbf,
                                              float* __restrict__ gram) {
    const int tid = threadIdx.x;
    const int id = blockIdx.x;              // b*2080 + t
    const int b = (id >= 2080) ? 1 : 0;
    const int t = id - b * 2080;
    int k = (int)((sqrtf(8.f * (float)t + 1.f) - 1.f) * 0.5f);
    while ((k + 1) * (k + 2) / 2 <= t) k++;
    while (k * (k + 1) / 2 > t) k--;
    const int j = t - k * (k + 1) / 2;

    const short* pa = kbf + ((size_t)b * KK + k) * HW + tid * 16;
    const short* pb = kbf + ((size_t)b * KK + j) * HW + tid * 16;
    const s16x8 a0 = *(const s16x8*)pa, a1 = *(const s16x8*)(pa + 8);
    const s16x8 b0 = *(const s16x8*)pb, b1 = *(const s16x8*)(pb + 8);
    float s = 0.f;
#pragma unroll
    for (int i = 0; i < 8; i++) {
        s = fmaf(bf2f(a0[i]), bf2f(b0[i]), s);
        s = fmaf(bf2f(a1[i]), bf2f(b1[i]), s);
    }
#pragma unroll
    for (int off = 32; off; off >>= 1) s += __shfl_down(s, off, 64);
    __shared__ float red[4];
    if ((tid & 63) == 0) red[tid >> 6] = s;
    __syncthreads();
    if (tid == 0) {
        const float tot = red[0] + red[1] + red[2] + red[3];
        gram[((size_t)b * KK + k) * KK + j] = tot;
        gram[((size_t)b * KK + j) * KK + k] = tot;
    }
}

// ---------------------------------------------------------------------------
// K3: gates only: beta/alpha per (b,n,k,h). Block per (b,n,k), thread = c.
// ---------------------------------------------------------------------------
__global__ __launch_bounds__(256) void k_gates(const float* __restrict__ state,
                                               const float* __restrict__ b_w,
                                               const float* __restrict__ a_w,
                                               const float* __restrict__ A_log,
                                               const float* __restrict__ dt_bias,
                                               float* __restrict__ betaH,
                                               float* __restrict__ alphaH) {
    const int tid = threadIdx.x;   // c
    const int id = blockIdx.x;     // (b*N+n)*K + k
    const int k = id & 63;
    const int bn = id >> 6;
    const float s = state[((size_t)bn * KK + k) * CC + tid];

    float pb[NH], pa[NH];
#pragma unroll
    for (int h = 0; h < NH; h++) {
        pb[h] = s * b_w[h * CC + tid];
        pa[h] = s * a_w[h * CC + tid];
    }
#pragma unroll
    for (int off = 32; off; off >>= 1) {
#pragma unroll
        for (int h = 0; h < NH; h++) {
            pb[h] += __shfl_down(pb[h], off, 64);
            pa[h] += __shfl_down(pa[h], off, 64);
        }
    }
    __shared__ float red[4][2 * NH];
    const int wave = tid >> 6, lane = tid & 63;
    if (lane == 0) {
#pragma unroll
        for (int h = 0; h < NH; h++) { red[wave][h] = pb[h]; red[wave][NH + h] = pa[h]; }
    }
    __syncthreads();
    const int h = tid >> 5;
    float braw = 0.f, araw = 0.f;
#pragma unroll
    for (int w = 0; w < 4; w++) { braw += red[w][h]; araw += red[w][NH + h]; }
    if ((tid & 31) == 0) {
        const float beta = 1.f / (1.f + __expf(-braw));
        const float xx = araw + dt_bias[h];
        const float sp = fmaxf(xx, 0.f) + log1pf(__expf(-fabsf(xx)));   // softplus
        const float alpha = -__expf(A_log[h]) * sp;
        betaH[(size_t)id * NH + h] = beta;
        alphaH[(size_t)id * NH + h] = alpha;
    }
}

// ---------------------------------------------------------------------------
// K4a (MFMA, split-K): partial vkt over one hw-eighth (512 hw).
// Grid = bn(32) x ct(16) x hs(8) = 4096 blocks (16/CU) -> TLP hides HBM
// latency. Each of 4 waves covers 128 hw = 4 k-steps: all 24 loads issued
// up-front (straight-line), 16 MFMA, LDS cross-wave reduce, 4KB f32 partial.
// value is read exactly once from HBM (disjoint across blocks).
// ---------------------------------------------------------------------------
__global__ __launch_bounds__(256) void k_vkt_part(const short* __restrict__ kbf,
                                                  const float* __restrict__ value,
                                                  float* __restrict__ pbuf) {
    const int tid = threadIdx.x;
    const int id = blockIdx.x;        // (bn*16 + ct)*8 + hs
    const int hs = id & 7;
    const int ct = (id >> 3) & 15;
    const int bn = id >> 7;
    const int b  = bn >> 4;
    const int w = tid >> 6, lane = tid & 63;
    const int l15 = lane & 15, hi = lane >> 4;
    const int ko  = hi << 3;          // K offset within fragment: 0,8,16,24
    const int hwbase = hs * 512 + w * 128;

    const short* Ap = kbf + (size_t)b * KK * HW + hwbase + ko;
    const float* Vp = value + ((size_t)bn * CC + ct * 16 + l15) * HW + hwbase + ko;

    // issue ALL loads first (no loop-carried regs, TLP covers latency)
    s16x8 a[4][4];    // [k-step][m]
    f32x4 v[4][2];    // [k-step][half]
#pragma unroll
    for (int s = 0; s < 4; s++) {
#pragma unroll
        for (int m = 0; m < 4; m++)
            a[s][m] = *(const s16x8*)(Ap + (size_t)(m * 16 + l15) * HW + s * 32);
        const float* p = Vp + s * 32;
        v[s][0] = *(const f32x4*)p;
        v[s][1] = *(const f32x4*)(p + 4);
    }

    f32x4 acc[4];
#pragma unroll
    for (int m = 0; m < 4; m++) acc[m] = (f32x4){0.f, 0.f, 0.f, 0.f};
#pragma unroll
    for (int s = 0; s < 4; s++) {
        s16x8 bfr;
#pragma unroll
        for (int j = 0; j < 4; j++) { bfr[j] = f2bf(v[s][0][j]); bfr[4 + j] = f2bf(v[s][1][j]); }
#pragma unroll
        for (int m = 0; m < 4; m++)
            acc[m] = __builtin_amdgcn_mfma_f32_16x16x32_bf16(a[s][m], bfr, acc[m], 0, 0, 0);
    }

    // cross-wave reduce (4 hw-quarters) -> one f32 partial tile [64k][16c]
    __shared__ float red[4][KK][17];
#pragma unroll
    for (int m = 0; m < 4; m++)
#pragma unroll
        for (int r = 0; r < 4; r++)
            red[w][m * 16 + hi * 4 + r][l15] = acc[m][r];
    __syncthreads();

    const int k = tid >> 2, cq = (tid & 3) * 4;
    f32x4 o;
#pragma unroll
    for (int i = 0; i < 4; i++)
        o[i] = red[0][k][cq + i] + red[1][k][cq + i] + red[2][k][cq + i] + red[3][k][cq + i];
    *(f32x4*)(pbuf + (size_t)id * 1024 + k * 16 + cq) = o;
}

// ---------------------------------------------------------------------------
// K4b: combine 8 partials + v_k = gram@state + gates ->
//      ns = alpha*(state - beta*v_k) + beta*vkt, stored bf16 nsT[bn][c][k].
// Grid = bn(32) x ct(16) = 512 blocks.
// ---------------------------------------------------------------------------
__global__ __launch_bounds__(256) void k_combine(const float* __restrict__ pbuf,
                                                 const float* __restrict__ gram,
                                                 const float* __restrict__ state,
                                                 const float* __restrict__ betaH,
                                                 const float* __restrict__ alphaH,
                                                 short* __restrict__ nsT) {
    const int tid = threadIdx.x;
    const int id = blockIdx.x;        // bn*16 + ct
    const int ct = id & 15;
    const int bn = id >> 4;
    const int b  = bn >> 4;
    const int head = ct >> 1;

    __shared__ float gramL[KK][65];
    __shared__ float stL[KK][17];
    __shared__ float alphaL[KK], betaL[KK];
    __shared__ float nsb[KK][17];

    for (int i = tid; i < KK * KK; i += 256)
        gramL[i >> 6][i & 63] = gram[(size_t)b * KK * KK + i];
    for (int i = tid; i < KK * 16; i += 256)
        stL[i >> 4][i & 15] = state[((size_t)bn * KK + (i >> 4)) * CC + ct * 16 + (i & 15)];
    if (tid < KK) {
        alphaL[tid] = alphaH[((size_t)bn * KK + tid) * NH + head];
        betaL[tid]  = betaH[((size_t)bn * KK + tid) * NH + head];
    }
    __syncthreads();

    const int k = tid >> 2, cq = (tid & 3) * 4;

    // sum 8 hw-partials
    f32x4 vkt = (f32x4){0.f, 0.f, 0.f, 0.f};
#pragma unroll
    for (int hs = 0; hs < 8; hs++) {
        const f32x4 p = *(const f32x4*)(pbuf + ((size_t)id * 8 + hs) * 1024 + k * 16 + cq);
        vkt += p;
    }

    float vk[4] = {0.f, 0.f, 0.f, 0.f};
#pragma unroll 8
    for (int j = 0; j < KK; j++) {
        const float g = gramL[k][j];
        vk[0] = fmaf(g, stL[j][cq + 0], vk[0]);
        vk[1] = fmaf(g, stL[j][cq + 1], vk[1]);
        vk[2] = fmaf(g, stL[j][cq + 2], vk[2]);
        vk[3] = fmaf(g, stL[j][cq + 3], vk[3]);
    }
    const float al = alphaL[k], be = betaL[k];
#pragma unroll
    for (int i = 0; i < 4; i++)
        nsb[k][cq + i] = al * (stL[k][cq + i] - be * vk[i]) + be * vkt[i];
    __syncthreads();

    const int c = tid >> 4, k4 = (tid & 15) * 4;
    s16x4 v;
#pragma unroll
    for (int i = 0; i < 4; i++) v[i] = f2bf(nsb[k4 + i][c]);
    *(s16x4*)(nsT + ((size_t)bn * CC + ct * 16 + c) * KK + k4) = v;
}

// ---------------------------------------------------------------------------
// K5 (MFMA): readout[b,n,c,hw] = sum_k kn[b,k,hw] * ns[b,n,k,c]
// A = nsT[c][k] (m=c), B = kbfT[hw][k] (n=hw). Pure-register, no LDS/sync.
// ---------------------------------------------------------------------------
__global__ __launch_bounds__(256) void k_readout_mfma(const short* __restrict__ kbfT,
                                                      const short* __restrict__ nsT,
                                                      float* __restrict__ out) {
    const int tid = threadIdx.x;
    const int id = blockIdx.x;          // bn*64 + hwt
    const int hwt = id & 63;
    const int bn  = id >> 6;
    const int b   = bn >> 4;
    const int w = tid >> 6, lane = tid & 63;
    const int l15 = lane & 15, hi = lane >> 4;
    const int hw0 = hwt * 64 + w * 16;

    const short* Bp = kbfT + ((size_t)b * HW + hw0 + l15) * KK + hi * 8;
    const s16x8 b0 = *(const s16x8*)Bp;
    const s16x8 b1 = *(const s16x8*)(Bp + 32);

    const short* Ap = nsT + ((size_t)bn * CC + l15) * KK + hi * 8;
    float* op = out + ((size_t)bn * CC + hi * 4) * HW + hw0 + l15;

#pragma unroll
    for (int ct = 0; ct < 16; ct++) {
        const s16x8 a0 = *(const s16x8*)(Ap + (size_t)(ct * 16) * KK);
        const s16x8 a1 = *(const s16x8*)(Ap + (size_t)(ct * 16) * KK + 32);
        f32x4 acc = (f32x4){0.f, 0.f, 0.f, 0.f};
        acc = __builtin_amdgcn_mfma_f32_16x16x32_bf16(a0, b0, acc, 0, 0, 0);
        acc = __builtin_amdgcn_mfma_f32_16x16x32_bf16(a1, b1, acc, 0, 0, 0);
#pragma unroll
        for (int r = 0; r < 4; r++)
            op[(size_t)(ct * 16 + r) * HW] = acc[r];
    }
}

// ---------------------------------------------------------------------------
extern "C" void kernel_launch(void* const* d_in, const int* in_sizes, int n_in,
                              void* d_out, int out_size, void* d_ws, size_t ws_size,
                              hipStream_t stream) {
    const float* value   = (const float*)d_in[0];
    const float* key_map = (const float*)d_in[1];
    const float* state   = (const float*)d_in[2];
    const float* b_w     = (const float*)d_in[3];
    const float* a_w     = (const float*)d_in[4];
    const float* A_log   = (const float*)d_in[5];
    const float* dt_bias = (const float*)d_in[6];
    float* out = (float*)d_out;

    short* kbf   = (short*)d_ws;              // B*K*HW bf16     = 524288 sh
    short* kbfT  = kbf + 524288;              // B*HW*K bf16     = 524288 sh
    float* gram  = (float*)(kbfT + 524288);   // B*K*K           =   8192 f32
    float* betaH = gram + 8192;               // B*N*K*NH        =  16384 f32
    float* alphaH= betaH + 16384;             // B*N*K*NH        =  16384 f32
    short* nsT   = (short*)(alphaH + 16384);  // B*N*C*K bf16    = 524288 sh
    float* pbuf  = (float*)(nsT + 524288);    // 4096*1024 f32   = 16 MB
    // total ~19.3 MB of d_ws

    k_softmax<<<BB * (HW / 32), 64, 0, stream>>>(key_map, kbf, kbfT);
    k_gram<<<BB * (KK * (KK + 1) / 2), 256, 0, stream>>>(kbf, gram);
    k_gates<<<BB * NN * KK, 256, 0, stream>>>(state, b_w, a_w, A_log, dt_bias,
                                              betaH, alphaH);
    k_vkt_part<<<BB * NN * 16 * 8, 256, 0, stream>>>(kbf, value, pbuf);
    k_combine<<<BB * NN * 16, 256, 0, stream>>>(pbuf, gram, state, betaH, alphaH, nsT);
    k_readout_mfma<<<BB * NN * (HW / 64), 256, 0, stream>>>(kbfT, nsT, out);
}

// Round 7
// 111.865 us; speedup vs baseline: 1.1572x; 1.1572x over previous
//
#include <hip/hip_runtime.h>
#include <hip/hip_bf16.h>

// Shapes (fixed for this problem)
#define BB 2
#define NN 16
#define CC 256
#define KK 64
#define HW 4096
#define NH 8

typedef __attribute__((ext_vector_type(4))) float f32x4;
typedef __attribute__((ext_vector_type(8))) short s16x8;
typedef __attribute__((ext_vector_type(4))) short s16x4;

__device__ __forceinline__ short f2bf(float f) {
    __hip_bfloat16 h = __float2bfloat16(f);
    return *reinterpret_cast<short*>(&h);
}
__device__ __forceinline__ float bf2f(short s) {
    unsigned int u = ((unsigned int)(unsigned short)s) << 16;
    float f; __builtin_memcpy(&f, &u, 4); return f;
}

// ---------------------------------------------------------------------------
// K1: key_n = softmax(key_map, axis=K). Two lanes per hw (32 k each), shfl_xor
// combine. Emits kbf bf16 [b][k][hw] and kbfT bf16 [b][hw][k].
// ---------------------------------------------------------------------------
__global__ __launch_bounds__(64) void k_softmax(const float* __restrict__ km,
                                                short* __restrict__ kbf,
                                                short* __restrict__ kbfT) {
    const int b = blockIdx.x >> 7;                  // 128 blocks per b
    const int hw = (blockIdx.x & 127) * 32 + (threadIdx.x & 31);
    const int half = threadIdx.x >> 5;              // k in [half*32, half*32+32)
    const float* p = km + ((size_t)b * KK + half * 32) * HW + hw;
    float x[32];
    float m = -1e30f;
#pragma unroll
    for (int k = 0; k < 32; k++) { x[k] = p[(size_t)k * HW]; m = fmaxf(m, x[k]); }
    m = fmaxf(m, __shfl_xor(m, 32, 64));
    float s = 0.f;
#pragma unroll
    for (int k = 0; k < 32; k++) { x[k] = __expf(x[k] - m); s += x[k]; }
    s += __shfl_xor(s, 32, 64);
    const float inv = 1.f / s;
    short* q2 = kbf + ((size_t)b * KK + half * 32) * HW + hw;
#pragma unroll
    for (int k = 0; k < 32; k++) {
        x[k] *= inv;
        q2[(size_t)k * HW] = f2bf(x[k]);
    }
    short* q3 = kbfT + ((size_t)b * HW + hw) * KK + half * 32;
#pragma unroll
    for (int k8 = 0; k8 < 32; k8 += 8) {
        s16x8 v;
#pragma unroll
        for (int j = 0; j < 8; j++) v[j] = f2bf(x[k8 + j]);
        *(s16x8*)(q3 + k8) = v;
    }
}

// ---------------------------------------------------------------------------
// K2: gram[b,k,j] = sum_hw kn[b,k,hw]*kn[b,j,hw]. Symmetric (k>=j, mirror).
// ---------------------------------------------------------------------------
__global__ __launch_bounds__(256) void k_gram(const short* __restrict__ kbf,
                                              float* __restrict__ gram) {
    const int tid = threadIdx.x;
    const int id = blockIdx.x;              // b*2080 + t
    const int b = (id >= 2080) ? 1 : 0;
    const int t = id - b * 2080;
    int k = (int)((sqrtf(8.f * (float)t + 1.f) - 1.f) * 0.5f);
    while ((k + 1) * (k + 2) / 2 <= t) k++;
    while (k * (k + 1) / 2 > t) k--;
    const int j = t - k * (k + 1) / 2;

    const short* pa = kbf + ((size_t)b * KK + k) * HW + tid * 16;
    const short* pb = kbf + ((size_t)b * KK + j) * HW + tid * 16;
    const s16x8 a0 = *(const s16x8*)pa, a1 = *(const s16x8*)(pa + 8);
    const s16x8 b0 = *(const s16x8*)pb, b1 = *(const s16x8*)(pb + 8);
    float s = 0.f;
#pragma unroll
    for (int i = 0; i < 8; i++) {
        s = fmaf(bf2f(a0[i]), bf2f(b0[i]), s);
        s = fmaf(bf2f(a1[i]), bf2f(b1[i]), s);
    }
#pragma unroll
    for (int off = 32; off; off >>= 1) s += __shfl_down(s, off, 64);
    __shared__ float red[4];
    if ((tid & 63) == 0) red[tid >> 6] = s;
    __syncthreads();
    if (tid == 0) {
        const float tot = red[0] + red[1] + red[2] + red[3];
        gram[((size_t)b * KK + k) * KK + j] = tot;
        gram[((size_t)b * KK + j) * KK + k] = tot;
    }
}

// ---------------------------------------------------------------------------
// K3: gates only: beta/alpha per (b,n,k,h). Block per (b,n,k), thread = c.
// ---------------------------------------------------------------------------
__global__ __launch_bounds__(256) void k_gates(const float* __restrict__ state,
                                               const float* __restrict__ b_w,
                                               const float* __restrict__ a_w,
                                               const float* __restrict__ A_log,
                                               const float* __restrict__ dt_bias,
                                               float* __restrict__ betaH,
                                               float* __restrict__ alphaH) {
    const int tid = threadIdx.x;   // c
    const int id = blockIdx.x;     // (b*N+n)*K + k
    const int k = id & 63;
    const int bn = id >> 6;
    const float s = state[((size_t)bn * KK + k) * CC + tid];

    float pb[NH], pa[NH];
#pragma unroll
    for (int h = 0; h < NH; h++) {
        pb[h] = s * b_w[h * CC + tid];
        pa[h] = s * a_w[h * CC + tid];
    }
#pragma unroll
    for (int off = 32; off; off >>= 1) {
#pragma unroll
        for (int h = 0; h < NH; h++) {
            pb[h] += __shfl_down(pb[h], off, 64);
            pa[h] += __shfl_down(pa[h], off, 64);
        }
    }
    __shared__ float red[4][2 * NH];
    const int wave = tid >> 6, lane = tid & 63;
    if (lane == 0) {
#pragma unroll
        for (int h = 0; h < NH; h++) { red[wave][h] = pb[h]; red[wave][NH + h] = pa[h]; }
    }
    __syncthreads();
    const int h = tid >> 5;
    float braw = 0.f, araw = 0.f;
#pragma unroll
    for (int w = 0; w < 4; w++) { braw += red[w][h]; araw += red[w][NH + h]; }
    if ((tid & 31) == 0) {
        const float beta = 1.f / (1.f + __expf(-braw));
        const float xx = araw + dt_bias[h];
        const float sp = fmaxf(xx, 0.f) + log1pf(__expf(-fabsf(xx)));   // softplus
        const float alpha = -__expf(A_log[h]) * sp;
        betaH[(size_t)id * NH + h] = beta;
        alphaH[(size_t)id * NH + h] = alpha;
    }
}

// ---------------------------------------------------------------------------
// K4 (MFMA, fused): vkt[k,c] = sum_hw kn[k,hw]*value[c,hw] over hw=4096, then
// v_k = gram@state, ns = alpha*(state - beta*v_k) + beta*vkt -> bf16 nsT.
// Block per (b,n, 16-c tile): 512 blocks (2/CU), 4 waves; wave w owns k rows
// [16w,16w+16) over ALL hw (no cross-wave reduce).
// Pipeline: 16 steps x 256 hw; value reg-staged (T14) 2 steps ahead into a
// 2-buffer XOR-swizzled LDS f32 tile. Issue order per iter: A-loads (L2)
// first, stage-loads last -> MFMA's vmcnt wait never drains the prefetch.
// Raw s_barrier + manual lgkmcnt (no __syncthreads vmcnt(0) drain).
// ---------------------------------------------------------------------------
__global__ __launch_bounds__(256) void k_vkt_fused(const short* __restrict__ kbf,
                                                   const float* __restrict__ value,
                                                   const float* __restrict__ gram,
                                                   const float* __restrict__ state,
                                                   const float* __restrict__ betaH,
                                                   const float* __restrict__ alphaH,
                                                   short* __restrict__ nsT) {
    const int tid = threadIdx.x;
    const int id = blockIdx.x;        // bn*16 + ct
    const int ct = id & 15;
    const int bn = id >> 4;
    const int b  = bn >> 4;
    const int head = ct >> 1;
    const int w = tid >> 6, lane = tid & 63;
    const int l15 = lane & 15, hi = lane >> 4;
    const int ko = hi << 3;
    const int d = l15 & 7;            // read-side swizzle key (row = l15)

    __shared__ float Vs[2][16][256];  // 32 KB, XOR-swizzled chunks

    // A: kn row = w*16 + l15 (L2-resident)
    const short* Ap = kbf + ((size_t)(b * KK + w * 16 + l15)) * HW + ko;

    // staging: wave w stages rows c = 4w..4w+3; global load at chunk=lane
    // (coalesced), ds_write at phys chunk = lane ^ (c&7).
    const float* Vrow[4];
    int dsw[4];
#pragma unroll
    for (int i = 0; i < 4; i++) {
        const int c = w * 4 + i;
        Vrow[i] = value + ((size_t)(bn * CC + ct * 16 + c)) * HW + lane * 4;
        dsw[i] = c * 256 + ((lane ^ (c & 7)) << 2);
    }

    f32x4 stg[2][4];
    f32x4 acc = (f32x4){0.f, 0.f, 0.f, 0.f};

#define LDREG(ph_, t_)                                                         \
    { _Pragma("unroll") for (int i = 0; i < 4; i++)                            \
          stg[ph_][i] = *(const f32x4*)(Vrow[i] + (t_) * 256); }
#define DSWR(ph_, nb_)                                                         \
    { _Pragma("unroll") for (int i = 0; i < 4; i++)                            \
          *(f32x4*)(&Vs[0][0][0] + (nb_) * 4096 + dsw[i]) = stg[ph_][i]; }

    LDREG(0, 0);
    LDREG(1, 1);
    DSWR(0, 0);                                     // waits only stg[0] (vmcnt(4))
    asm volatile("s_waitcnt lgkmcnt(0)" ::: "memory");
    __builtin_amdgcn_s_barrier();

#pragma unroll
    for (int t = 0; t < 16; t++) {
        const int ph = t & 1, nx = ph ^ 1;
        // A-loads FIRST (oldest) so MFMA's vmcnt wait leaves stage loads alive
        s16x8 areg[8];
#pragma unroll
        for (int s = 0; s < 8; s++)
            areg[s] = *(const s16x8*)(Ap + (size_t)t * 256 + s * 32);
        if (t + 2 < 16) LDREG(ph, t + 2);           // HBM prefetch, 2 steps ahead

#pragma unroll
        for (int s = 0; s < 8; s++) {
            const int j0 = 8 * s + hi * 2;          // logical 16B chunk
            const f32x4 v0 = *(const f32x4*)&Vs[ph][l15][((j0) ^ d) << 2];
            const f32x4 v1 = *(const f32x4*)&Vs[ph][l15][((j0 + 1) ^ d) << 2];
            s16x8 bf;
#pragma unroll
            for (int e = 0; e < 4; e++) { bf[e] = f2bf(v0[e]); bf[4 + e] = f2bf(v1[e]); }
            acc = __builtin_amdgcn_mfma_f32_16x16x32_bf16(areg[s], bf, acc, 0, 0, 0);
        }
        asm volatile("s_waitcnt lgkmcnt(0)" ::: "memory");
        __builtin_amdgcn_s_barrier();               // everyone done reading buf[ph]
        if (t + 1 < 16) {
            DSWR(nx, nx);                           // step t+1 data (issued iter t-1)
            asm volatile("s_waitcnt lgkmcnt(0)" ::: "memory");
            __builtin_amdgcn_s_barrier();           // buf[nx] visible for step t+1
        }
    }
#undef LDREG
#undef DSWR

    // --- epilogue: vkt tile -> LDS, then fused combine (gram@state + gates)
    __shared__ float vktL[KK][17];
#pragma unroll
    for (int r = 0; r < 4; r++) vktL[w * 16 + hi * 4 + r][l15] = acc[r];

    __shared__ float gramL[KK][65];
    __shared__ float stL[KK][17];
    __shared__ float alphaL[KK], betaL[KK];
    __shared__ float nsb[KK][17];
    for (int i = tid; i < KK * KK; i += 256)
        gramL[i >> 6][i & 63] = gram[(size_t)b * KK * KK + i];
    for (int i = tid; i < KK * 16; i += 256)
        stL[i >> 4][i & 15] = state[((size_t)bn * KK + (i >> 4)) * CC + ct * 16 + (i & 15)];
    if (tid < KK) {
        alphaL[tid] = alphaH[((size_t)bn * KK + tid) * NH + head];
        betaL[tid]  = betaH[((size_t)bn * KK + tid) * NH + head];
    }
    __syncthreads();

    const int k = tid >> 2, cq = (tid & 3) * 4;
    float vk[4] = {0.f, 0.f, 0.f, 0.f};
#pragma unroll 8
    for (int j = 0; j < KK; j++) {
        const float g = gramL[k][j];
        vk[0] = fmaf(g, stL[j][cq + 0], vk[0]);
        vk[1] = fmaf(g, stL[j][cq + 1], vk[1]);
        vk[2] = fmaf(g, stL[j][cq + 2], vk[2]);
        vk[3] = fmaf(g, stL[j][cq + 3], vk[3]);
    }
    const float al = alphaL[k], be = betaL[k];
#pragma unroll
    for (int i = 0; i < 4; i++)
        nsb[k][cq + i] = al * (stL[k][cq + i] - be * vk[i]) + be * vktL[k][cq + i];
    __syncthreads();

    const int c = tid >> 4, k4 = (tid & 15) * 4;
    s16x4 v;
#pragma unroll
    for (int i = 0; i < 4; i++) v[i] = f2bf(nsb[k4 + i][c]);
    *(s16x4*)(nsT + ((size_t)bn * CC + ct * 16 + c) * KK + k4) = v;
}

// ---------------------------------------------------------------------------
// K5 (MFMA): readout[b,n,c,hw] = sum_k kn[b,k,hw] * ns[b,n,k,c]
// A = nsT[c][k] (m=c), B = kbfT[hw][k] (n=hw). Pure-register, no LDS/sync.
// ---------------------------------------------------------------------------
__global__ __launch_bounds__(256) void k_readout_mfma(const short* __restrict__ kbfT,
                                                      const short* __restrict__ nsT,
                                                      float* __restrict__ out) {
    const int tid = threadIdx.x;
    const int id = blockIdx.x;          // bn*64 + hwt
    const int hwt = id & 63;
    const int bn  = id >> 6;
    const int b   = bn >> 4;
    const int w = tid >> 6, lane = tid & 63;
    const int l15 = lane & 15, hi = lane >> 4;
    const int hw0 = hwt * 64 + w * 16;

    const short* Bp = kbfT + ((size_t)b * HW + hw0 + l15) * KK + hi * 8;
    const s16x8 b0 = *(const s16x8*)Bp;
    const s16x8 b1 = *(const s16x8*)(Bp + 32);

    const short* Ap = nsT + ((size_t)bn * CC + l15) * KK + hi * 8;
    float* op = out + ((size_t)bn * CC + hi * 4) * HW + hw0 + l15;

#pragma unroll
    for (int ct = 0; ct < 16; ct++) {
        const s16x8 a0 = *(const s16x8*)(Ap + (size_t)(ct * 16) * KK);
        const s16x8 a1 = *(const s16x8*)(Ap + (size_t)(ct * 16) * KK + 32);
        f32x4 acc = (f32x4){0.f, 0.f, 0.f, 0.f};
        acc = __builtin_amdgcn_mfma_f32_16x16x32_bf16(a0, b0, acc, 0, 0, 0);
        acc = __builtin_amdgcn_mfma_f32_16x16x32_bf16(a1, b1, acc, 0, 0, 0);
#pragma unroll
        for (int r = 0; r < 4; r++)
            op[(size_t)(ct * 16 + r) * HW] = acc[r];
    }
}

// ---------------------------------------------------------------------------
extern "C" void kernel_launch(void* const* d_in, const int* in_sizes, int n_in,
                              void* d_out, int out_size, void* d_ws, size_t ws_size,
                              hipStream_t stream) {
    const float* value   = (const float*)d_in[0];
    const float* key_map = (const float*)d_in[1];
    const float* state   = (const float*)d_in[2];
    const float* b_w     = (const float*)d_in[3];
    const float* a_w     = (const float*)d_in[4];
    const float* A_log   = (const float*)d_in[5];
    const float* dt_bias = (const float*)d_in[6];
    float* out = (float*)d_out;

    short* kbf   = (short*)d_ws;              // B*K*HW bf16     = 524288 sh
    short* kbfT  = kbf + 524288;              // B*HW*K bf16     = 524288 sh
    float* gram  = (float*)(kbfT + 524288);   // B*K*K           =   8192 f32
    float* betaH = gram + 8192;               // B*N*K*NH        =  16384 f32
    float* alphaH= betaH + 16384;             // B*N*K*NH        =  16384 f32
    short* nsT   = (short*)(alphaH + 16384);  // B*N*C*K bf16    = 524288 sh
    // total ~3.3 MB of d_ws

    k_softmax<<<BB * (HW / 32), 64, 0, stream>>>(key_map, kbf, kbfT);
    k_gram<<<BB * (KK * (KK + 1) / 2), 256, 0, stream>>>(kbf, gram);
    k_gates<<<BB * NN * KK, 256, 0, stream>>>(state, b_w, a_w, A_log, dt_bias,
                                              betaH, alphaH);
    k_vkt_fused<<<BB * NN * (CC / 16), 256, 0, stream>>>(kbf, value, gram, state,
                                                         betaH, alphaH, nsT);
    k_readout_mfma<<<BB * NN * (HW / 64), 256, 0, stream>>>(kbfT, nsT, out);
}